// Round 1
// baseline (2005.988 us; speedup 1.0000x reference)
//
#include <hip/hip_runtime.h>
#include <math.h>

#define BB 8
#define SS 2048
#define DM 128
#define NH 4
#define DKH 32
#define NL 2
#define NROWS (BB*SS)   // 16384

__device__ __forceinline__ float kscale() { return 0.17677669529663687f; } // 1/sqrt(32)
#define LNEPS 1e-8f

// ---------------- mask: x = seqs * (log_seqs != 0) ----------------
__global__ __launch_bounds__(256) void mask_kernel(const float* __restrict__ seqs,
                                                   const int* __restrict__ logs,
                                                   float* __restrict__ x) {
    int i4 = blockIdx.x * 256 + threadIdx.x;   // float4 index, total N*D/4
    int row = i4 >> 5;                          // 32 float4 per row
    float4 v = ((const float4*)seqs)[i4];
    float km = (logs[row] != 0) ? 1.0f : 0.0f;
    v.x *= km; v.y *= km; v.z *= km; v.w *= km;
    ((float4*)x)[i4] = v;
}

// ---------------- layernorm over last dim (128); one wave per row ----------------
template<bool HAS_RES, bool HAS_KEEP>
__global__ __launch_bounds__(256) void ln_kernel(const float* __restrict__ X,
                                                 const float* __restrict__ R,
                                                 const float* __restrict__ g,
                                                 const float* __restrict__ bb,
                                                 const int* __restrict__ logs,
                                                 float* __restrict__ Y) {
    int wave = threadIdx.x >> 6, lane = threadIdx.x & 63;
    int row = blockIdx.x * 4 + wave;
    const float2* xp = (const float2*)(X + (size_t)row * DM);
    float2 xv = xp[lane];
    if (HAS_RES) {
        float2 rv = ((const float2*)(R + (size_t)row * DM))[lane];
        xv.x += rv.x; xv.y += rv.y;
    }
    float s = xv.x + xv.y;
    #pragma unroll
    for (int off = 1; off < 64; off <<= 1) s += __shfl_xor(s, off);
    float mean = s * (1.0f / DM);
    float dx = xv.x - mean, dy = xv.y - mean;
    float vs = dx * dx + dy * dy;
    #pragma unroll
    for (int off = 1; off < 64; off <<= 1) vs += __shfl_xor(vs, off);
    float rstd = rsqrtf(vs * (1.0f / DM) + LNEPS);
    float2 gv = ((const float2*)g)[lane];
    float2 bv = ((const float2*)bb)[lane];
    float y0 = dx * rstd * gv.x + bv.x;
    float y1 = dy * rstd * gv.y + bv.y;
    if (HAS_KEEP) {
        float km = (logs[row] != 0) ? 1.0f : 0.0f;
        y0 *= km; y1 *= km;
    }
    float2 o; o.x = y0; o.y = y1;
    ((float2*)(Y + (size_t)row * DM))[lane] = o;
}

// ---------------- GEMM: C[N,128] = op(A[N,128] @ W[128,128] + bias) ----------------
// tile: 64 rows x 128 cols, 256 threads, whole A-tile + whole W staged in LDS
template<bool RELU, bool HAS_RES, bool HAS_KEEP>
__global__ __launch_bounds__(256) void gemm128_kernel(const float* __restrict__ A,
                                                      const float* __restrict__ W,
                                                      const float* __restrict__ bias,
                                                      const float* __restrict__ R,
                                                      const int* __restrict__ logs,
                                                      float* __restrict__ C) {
    __shared__ float As[64 * 128];   // 32 KB
    __shared__ float Ws[128 * 128];  // 64 KB
    int tid = threadIdx.x;
    int rbase = blockIdx.x * 64;

    const float4* Ag = (const float4*)(A + (size_t)rbase * DM);
    float4* As4 = (float4*)As;
    #pragma unroll
    for (int i = 0; i < 8; i++) As4[tid + i * 256] = Ag[tid + i * 256];
    const float4* Wg = (const float4*)W;
    float4* Ws4 = (float4*)Ws;
    #pragma unroll
    for (int i = 0; i < 16; i++) Ws4[tid + i * 256] = Wg[tid + i * 256];
    __syncthreads();

    int tx = tid & 31, ty = tid >> 5;   // tx: col group (4 cols), ty: row group (8 rows)
    float acc[8][4];
    #pragma unroll
    for (int r = 0; r < 8; r++)
        #pragma unroll
        for (int c = 0; c < 4; c++) acc[r][c] = 0.0f;

    for (int k0 = 0; k0 < 128; k0 += 4) {
        float4 w0 = *(const float4*)&Ws[(k0 + 0) * 128 + tx * 4];
        float4 w1 = *(const float4*)&Ws[(k0 + 1) * 128 + tx * 4];
        float4 w2 = *(const float4*)&Ws[(k0 + 2) * 128 + tx * 4];
        float4 w3 = *(const float4*)&Ws[(k0 + 3) * 128 + tx * 4];
        #pragma unroll
        for (int r = 0; r < 8; r++) {
            float4 av = *(const float4*)&As[(ty * 8 + r) * 128 + k0];
            acc[r][0] += av.x * w0.x; acc[r][1] += av.x * w0.y; acc[r][2] += av.x * w0.z; acc[r][3] += av.x * w0.w;
            acc[r][0] += av.y * w1.x; acc[r][1] += av.y * w1.y; acc[r][2] += av.y * w1.z; acc[r][3] += av.y * w1.w;
            acc[r][0] += av.z * w2.x; acc[r][1] += av.z * w2.y; acc[r][2] += av.z * w2.z; acc[r][3] += av.z * w2.w;
            acc[r][0] += av.w * w3.x; acc[r][1] += av.w * w3.y; acc[r][2] += av.w * w3.z; acc[r][3] += av.w * w3.w;
        }
    }

    float4 bv = *(const float4*)&bias[tx * 4];
    #pragma unroll
    for (int r = 0; r < 8; r++) {
        int row = rbase + ty * 8 + r;
        float o0 = acc[r][0] + bv.x;
        float o1 = acc[r][1] + bv.y;
        float o2 = acc[r][2] + bv.z;
        float o3 = acc[r][3] + bv.w;
        if (RELU) {
            o0 = fmaxf(o0, 0.0f); o1 = fmaxf(o1, 0.0f);
            o2 = fmaxf(o2, 0.0f); o3 = fmaxf(o3, 0.0f);
        }
        if (HAS_RES) {
            float4 rv = *(const float4*)&R[(size_t)row * DM + tx * 4];
            o0 += rv.x; o1 += rv.y; o2 += rv.z; o3 += rv.w;
        }
        if (HAS_KEEP) {
            float km = (logs[row] != 0) ? 1.0f : 0.0f;
            o0 *= km; o1 *= km; o2 *= km; o3 *= km;
        }
        float4 ov; ov.x = o0; ov.y = o1; ov.z = o2; ov.w = o3;
        *(float4*)&C[(size_t)row * DM + tx * 4] = ov;
    }
}

// ---------------- causal flash attention, fp32; one thread = one q row ----------------
// grid: (S/256, H, B), block 256 = 4 waves; K/V tiles of 64 rows staged in LDS
__global__ __launch_bounds__(256) void attn_kernel(const float* __restrict__ Q,
                                                   const float* __restrict__ K,
                                                   const float* __restrict__ V,
                                                   float* __restrict__ O) {
    __shared__ float Ks[64][32];
    __shared__ float Vs[64][32];
    int tid = threadIdx.x;
    int qt = blockIdx.x, h = blockIdx.y, b = blockIdx.z;
    int wave = tid >> 6, lane = tid & 63;
    int srow = qt * 256 + wave * 64 + lane;
    size_t qoff = ((size_t)(b * SS + srow)) * DM + h * DKH;

    float qv[32];
    #pragma unroll
    for (int c4 = 0; c4 < 8; c4++) {
        float4 t4 = *(const float4*)&Q[qoff + c4 * 4];
        qv[c4 * 4 + 0] = t4.x; qv[c4 * 4 + 1] = t4.y;
        qv[c4 * 4 + 2] = t4.z; qv[c4 * 4 + 3] = t4.w;
    }
    float m = -1e30f, l = 0.0f;
    float acc[32];
    #pragma unroll
    for (int c = 0; c < 32; c++) acc[c] = 0.0f;

    int ntiles = qt * 4 + 4;
    for (int t = 0; t < ntiles; t++) {
        __syncthreads();
        #pragma unroll
        for (int i = 0; i < 2; i++) {
            int f = tid * 2 + i;          // 0..511
            int j = f >> 3, c4 = f & 7;
            size_t g = ((size_t)(b * SS + t * 64 + j)) * DM + h * DKH + c4 * 4;
            *(float4*)&Ks[j][c4 * 4] = *(const float4*)&K[g];
            *(float4*)&Vs[j][c4 * 4] = *(const float4*)&V[g];
        }
        __syncthreads();
        int kbase = t * 64;
        for (int j = 0; j < 64; j++) {
            int kj = kbase + j;
            if (kj > srow) break;
            float sdot = 0.0f;
            #pragma unroll
            for (int c4 = 0; c4 < 8; c4++) {
                float4 k4 = *(const float4*)&Ks[j][c4 * 4];
                sdot += qv[c4 * 4 + 0] * k4.x + qv[c4 * 4 + 1] * k4.y
                      + qv[c4 * 4 + 2] * k4.z + qv[c4 * 4 + 3] * k4.w;
            }
            sdot *= kscale();
            float mn = fmaxf(m, sdot);
            float corr = __expf(m - mn);
            float p = __expf(sdot - mn);
            l = l * corr + p;
            #pragma unroll
            for (int c4 = 0; c4 < 8; c4++) {
                float4 v4 = *(const float4*)&Vs[j][c4 * 4];
                acc[c4 * 4 + 0] = acc[c4 * 4 + 0] * corr + p * v4.x;
                acc[c4 * 4 + 1] = acc[c4 * 4 + 1] * corr + p * v4.y;
                acc[c4 * 4 + 2] = acc[c4 * 4 + 2] * corr + p * v4.z;
                acc[c4 * 4 + 3] = acc[c4 * 4 + 3] * corr + p * v4.w;
            }
            m = mn;
        }
    }
    float inv = 1.0f / l;
    #pragma unroll
    for (int c4 = 0; c4 < 8; c4++) {
        float4 t4;
        t4.x = acc[c4 * 4 + 0] * inv; t4.y = acc[c4 * 4 + 1] * inv;
        t4.z = acc[c4 * 4 + 2] * inv; t4.w = acc[c4 * 4 + 3] * inv;
        *(float4*)&O[qoff + c4 * 4] = t4;
    }
}

extern "C" void kernel_launch(void* const* d_in, const int* in_sizes, int n_in,
                              void* d_out, int out_size, void* d_ws, size_t ws_size,
                              hipStream_t stream) {
    const int*   logs = (const int*)d_in[0];
    const float* seqs = (const float*)d_in[1];
    const float* Wqkv = (const float*)d_in[2];
    const float* bqkv = (const float*)d_in[3];
    const float* ln1g = (const float*)d_in[4];
    const float* ln1b = (const float*)d_in[5];
    const float* ln2g = (const float*)d_in[6];
    const float* ln2b = (const float*)d_in[7];
    const float* W1   = (const float*)d_in[8];
    const float* b1   = (const float*)d_in[9];
    const float* W2   = (const float*)d_in[10];
    const float* b2   = (const float*)d_in[11];
    const float* lng  = (const float*)d_in[12];
    const float* lnb  = (const float*)d_in[13];
    float* out = (float*)d_out;
    float* ws  = (float*)d_ws;

    size_t ND = (size_t)NROWS * DM;
    float* x    = ws;
    float* qin  = ws + ND;
    float* q    = ws + 2 * ND;
    float* k    = ws + 3 * ND;
    float* v    = ws + 4 * ND;
    float* o    = ws + 5 * ND;
    float* hbuf = ws + 6 * ND;

    mask_kernel<<<(NROWS * DM) / 4 / 256, 256, 0, stream>>>(seqs, logs, x);

    for (int i = 0; i < NL; i++) {
        const float* Wq = Wqkv + ((size_t)i * 3 + 0) * DM * DM;
        const float* Wk = Wqkv + ((size_t)i * 3 + 1) * DM * DM;
        const float* Wv = Wqkv + ((size_t)i * 3 + 2) * DM * DM;
        const float* bq = bqkv + ((size_t)i * 3 + 0) * DM;
        const float* bk = bqkv + ((size_t)i * 3 + 1) * DM;
        const float* bvp = bqkv + ((size_t)i * 3 + 2) * DM;

        ln_kernel<false, false><<<NROWS / 4, 256, 0, stream>>>(x, nullptr, ln1g + i * DM, ln1b + i * DM, nullptr, qin);

        gemm128_kernel<false, false, false><<<NROWS / 64, 256, 0, stream>>>(qin, Wq, bq, nullptr, nullptr, q);
        gemm128_kernel<false, false, false><<<NROWS / 64, 256, 0, stream>>>(x,   Wk, bk, nullptr, nullptr, k);
        gemm128_kernel<false, false, false><<<NROWS / 64, 256, 0, stream>>>(x,   Wv, bvp, nullptr, nullptr, v);

        attn_kernel<<<dim3(SS / 256, NH, BB), 256, 0, stream>>>(q, k, v, o);

        // x = LN(qin + attn)
        ln_kernel<true, false><<<NROWS / 4, 256, 0, stream>>>(qin, o, ln2g + i * DM, ln2b + i * DM, nullptr, x);

        // hbuf = relu(x @ W1 + b1)
        gemm128_kernel<true, false, false><<<NROWS / 64, 256, 0, stream>>>(x, W1 + (size_t)i * DM * DM, b1 + i * DM, nullptr, nullptr, hbuf);

        // x = (x + hbuf @ W2 + b2) * keep
        gemm128_kernel<false, true, true><<<NROWS / 64, 256, 0, stream>>>(hbuf, W2 + (size_t)i * DM * DM, b2 + i * DM, x, logs, x);
    }

    // out = LN(x) * keep
    ln_kernel<false, true><<<NROWS / 4, 256, 0, stream>>>(x, nullptr, lng, lnb, logs, out);
}

// Round 4
// 379.886 us; speedup vs baseline: 5.2805x; 5.2805x over previous
//
#include <hip/hip_runtime.h>
#include <math.h>

#define BB 8
#define SS 2048
#define DM 128
#define NH 4
#define DKH 32
#define NL 2
#define NROWS (BB*SS)   // 16384

typedef __attribute__((ext_vector_type(8))) short bf16x8;
typedef __attribute__((ext_vector_type(4))) short short4v;
typedef __attribute__((ext_vector_type(4))) float f32x4;

#define SCALE 0.17677669529663687f
#define LNEPS 1e-8f

// LDS row strides (shorts). K tile rows hold 32 dk; V^T/P rows hold 64 keys.
#define KSTR 40
#define VSTR 72
#define PSTR 72

__device__ __forceinline__ short f2bf(float f) {
    union { float f; unsigned u; } x; x.f = f;
    unsigned r = (x.u + 0x7fffu + ((x.u >> 16) & 1u)) >> 16;
    return (short)r;
}

// ---------------- mask: x = seqs * (log_seqs != 0) ----------------
__global__ __launch_bounds__(256) void mask_kernel(const float* __restrict__ seqs,
                                                   const int* __restrict__ logs,
                                                   float* __restrict__ x) {
    int i4 = blockIdx.x * 256 + threadIdx.x;
    int row = i4 >> 5;
    float4 v = ((const float4*)seqs)[i4];
    float km = (logs[row] != 0) ? 1.0f : 0.0f;
    v.x *= km; v.y *= km; v.z *= km; v.w *= km;
    ((float4*)x)[i4] = v;
}

// ---------------- layernorm over last dim (128); one wave per row ----------------
template<bool HAS_RES, bool HAS_KEEP>
__global__ __launch_bounds__(256) void ln_kernel(const float* __restrict__ X,
                                                 const float* __restrict__ R,
                                                 const float* __restrict__ g,
                                                 const float* __restrict__ bb,
                                                 const int* __restrict__ logs,
                                                 float* __restrict__ Y) {
    int wave = threadIdx.x >> 6, lane = threadIdx.x & 63;
    int row = blockIdx.x * 4 + wave;
    const float2* xp = (const float2*)(X + (size_t)row * DM);
    float2 xv = xp[lane];
    if (HAS_RES) {
        float2 rv = ((const float2*)(R + (size_t)row * DM))[lane];
        xv.x += rv.x; xv.y += rv.y;
    }
    float s = xv.x + xv.y;
    #pragma unroll
    for (int off = 1; off < 64; off <<= 1) s += __shfl_xor(s, off);
    float mean = s * (1.0f / DM);
    float dx = xv.x - mean, dy = xv.y - mean;
    float vs = dx * dx + dy * dy;
    #pragma unroll
    for (int off = 1; off < 64; off <<= 1) vs += __shfl_xor(vs, off);
    float rstd = rsqrtf(vs * (1.0f / DM) + LNEPS);
    float2 gv = ((const float2*)g)[lane];
    float2 bv = ((const float2*)bb)[lane];
    float y0 = dx * rstd * gv.x + bv.x;
    float y1 = dy * rstd * gv.y + bv.y;
    if (HAS_KEEP) {
        float km = (logs[row] != 0) ? 1.0f : 0.0f;
        y0 *= km; y1 *= km;
    }
    float2 o; o.x = y0; o.y = y1;
    ((float2*)(Y + (size_t)row * DM))[lane] = o;
}

// ---------------- GEMM: C[N,128] = op(A[N,128] @ W[128,128] + bias) ----------------
template<bool RELU, bool HAS_RES, bool HAS_KEEP, bool OUT_BF16>
__global__ __launch_bounds__(256) void gemm128_kernel(const float* __restrict__ A,
                                                      const float* __restrict__ W,
                                                      const float* __restrict__ bias,
                                                      const float* __restrict__ R,
                                                      const int* __restrict__ logs,
                                                      void* __restrict__ C) {
    __shared__ float As[64 * 128];
    __shared__ float Ws[128 * 128];
    int tid = threadIdx.x;
    int rbase = blockIdx.x * 64;

    const float4* Ag = (const float4*)(A + (size_t)rbase * DM);
    float4* As4 = (float4*)As;
    #pragma unroll
    for (int i = 0; i < 8; i++) As4[tid + i * 256] = Ag[tid + i * 256];
    const float4* Wg = (const float4*)W;
    float4* Ws4 = (float4*)Ws;
    #pragma unroll
    for (int i = 0; i < 16; i++) Ws4[tid + i * 256] = Wg[tid + i * 256];
    __syncthreads();

    int tx = tid & 31, ty = tid >> 5;
    float acc[8][4];
    #pragma unroll
    for (int r = 0; r < 8; r++)
        #pragma unroll
        for (int c = 0; c < 4; c++) acc[r][c] = 0.0f;

    for (int k0 = 0; k0 < 128; k0 += 4) {
        float4 w0 = *(const float4*)&Ws[(k0 + 0) * 128 + tx * 4];
        float4 w1 = *(const float4*)&Ws[(k0 + 1) * 128 + tx * 4];
        float4 w2 = *(const float4*)&Ws[(k0 + 2) * 128 + tx * 4];
        float4 w3 = *(const float4*)&Ws[(k0 + 3) * 128 + tx * 4];
        #pragma unroll
        for (int r = 0; r < 8; r++) {
            float4 av = *(const float4*)&As[(ty * 8 + r) * 128 + k0];
            acc[r][0] += av.x * w0.x; acc[r][1] += av.x * w0.y; acc[r][2] += av.x * w0.z; acc[r][3] += av.x * w0.w;
            acc[r][0] += av.y * w1.x; acc[r][1] += av.y * w1.y; acc[r][2] += av.y * w1.z; acc[r][3] += av.y * w1.w;
            acc[r][0] += av.z * w2.x; acc[r][1] += av.z * w2.y; acc[r][2] += av.z * w2.z; acc[r][3] += av.z * w2.w;
            acc[r][0] += av.w * w3.x; acc[r][1] += av.w * w3.y; acc[r][2] += av.w * w3.z; acc[r][3] += av.w * w3.w;
        }
    }

    float4 bv = *(const float4*)&bias[tx * 4];
    #pragma unroll
    for (int r = 0; r < 8; r++) {
        int row = rbase + ty * 8 + r;
        float o0 = acc[r][0] + bv.x;
        float o1 = acc[r][1] + bv.y;
        float o2 = acc[r][2] + bv.z;
        float o3 = acc[r][3] + bv.w;
        if (RELU) {
            o0 = fmaxf(o0, 0.0f); o1 = fmaxf(o1, 0.0f);
            o2 = fmaxf(o2, 0.0f); o3 = fmaxf(o3, 0.0f);
        }
        if (HAS_RES) {
            float4 rv = *(const float4*)&R[(size_t)row * DM + tx * 4];
            o0 += rv.x; o1 += rv.y; o2 += rv.z; o3 += rv.w;
        }
        if (HAS_KEEP) {
            float km = (logs[row] != 0) ? 1.0f : 0.0f;
            o0 *= km; o1 *= km; o2 *= km; o3 *= km;
        }
        if (OUT_BF16) {
            short4v ov = { f2bf(o0), f2bf(o1), f2bf(o2), f2bf(o3) };
            *(short4v*)&((short*)C)[(size_t)row * DM + tx * 4] = ov;
        } else {
            float4 ov; ov.x = o0; ov.y = o1; ov.z = o2; ov.w = o3;
            *(float4*)&((float*)C)[(size_t)row * DM + tx * 4] = ov;
        }
    }
}

// ---------------- MFMA flash attention (bf16 in, f32 out) ----------------
// grid: (S/128, H, B); block 256 = 4 waves, each wave owns 32 q-rows.
// Swapped layout: S^T = K.Q^T so all lane values share one q-row (q = lane&15).
// O^T = V^T.P^T so rescale is lane-uniform. P via per-wave LDS roundtrip.
__global__ __launch_bounds__(256) void attn_mfma_kernel(const short* __restrict__ Qg,
                                                        const short* __restrict__ Kg,
                                                        const short* __restrict__ Vg,
                                                        float* __restrict__ Og) {
    __shared__ short Ks[64 * KSTR];        // K tile, row-major [key][dk]
    __shared__ short Vt[32 * VSTR];        // V^T tile [dk][key]
    __shared__ short Pl[4 * 32 * PSTR];    // per-wave P [q][key]

    int tid = threadIdx.x;
    int qt = (gridDim.x - 1) - blockIdx.x;    // heavy (high-q) blocks dispatch first
    int h = blockIdx.y, b = blockIdx.z;
    int w = tid >> 6, l = tid & 63;
    int c = l & 15, g = l >> 4;

    int qbase = qt * 128;
    size_t bhoff = (size_t)b * SS * DM + (size_t)h * DKH;

    // Q fragments (held in registers for whole kernel)
    bf16x8 qf[2];
    #pragma unroll
    for (int s = 0; s < 2; s++) {
        int qrow = qbase + w * 32 + s * 16 + c;
        qf[s] = *(const bf16x8*)(Qg + bhoff + (size_t)qrow * DM + g * 8);
    }
    f32x4 acc[2][2];
    #pragma unroll
    for (int s = 0; s < 2; s++)
        #pragma unroll
        for (int t2 = 0; t2 < 2; t2++)
            acc[s][t2] = (f32x4){0.f, 0.f, 0.f, 0.f};
    float mrun[2] = {-1e30f, -1e30f};
    float lrun[2] = {0.f, 0.f};
    int qmax = qbase + w * 32 + 31;
    int ntiles = qt * 2 + 2;

    int kkey = tid >> 2, kpart = tid & 3;     // K staging map (coalesced global)
    int vkey = tid & 63, vpart = tid >> 6;    // V staging map (conflict-free LDS writes)

    for (int kt = 0; kt < ntiles; kt++) {
        int kb = kt * 64;
        __syncthreads();
        // stage K row-major
        bf16x8 kv8 = *(const bf16x8*)(Kg + bhoff + (size_t)(kb + kkey) * DM + kpart * 8);
        *(bf16x8*)&Ks[kkey * KSTR + kpart * 8] = kv8;
        // stage V transposed
        bf16x8 vv8 = *(const bf16x8*)(Vg + bhoff + (size_t)(kb + vkey) * DM + vpart * 8);
        #pragma unroll
        for (int j = 0; j < 8; j++) Vt[(vpart * 8 + j) * VSTR + vkey] = vv8[j];
        __syncthreads();
        if (kb > qmax) continue;

        // K fragments (shared across both q-subtiles)
        bf16x8 kf[4];
        #pragma unroll
        for (int t = 0; t < 4; t++)
            kf[t] = *(bf16x8*)&Ks[(t * 16 + c) * KSTR + g * 8];

        #pragma unroll
        for (int s = 0; s < 2; s++) {
            int qg = qbase + w * 32 + s * 16 + c;
            f32x4 z = {0.f, 0.f, 0.f, 0.f};
            f32x4 sc[4];
            #pragma unroll
            for (int t = 0; t < 4; t++)
                sc[t] = __builtin_amdgcn_mfma_f32_16x16x32_bf16(kf[t], qf[s], z, 0, 0, 0);
            // causal mask + online softmax (all values this lane = one q-row)
            float pv[16];
            float mx = -1e30f;
            #pragma unroll
            for (int t = 0; t < 4; t++)
                #pragma unroll
                for (int r = 0; r < 4; r++) {
                    int kg = kb + t * 16 + g * 4 + r;
                    float vs = (kg <= qg) ? sc[t][r] * SCALE : -1e30f;
                    pv[t * 4 + r] = vs;
                    mx = fmaxf(mx, vs);
                }
            mx = fmaxf(mx, __shfl_xor(mx, 16));
            mx = fmaxf(mx, __shfl_xor(mx, 32));
            float mn = fmaxf(mrun[s], mx);
            float corr = __expf(mrun[s] - mn);
            mrun[s] = mn;
            float rs = 0.f;
            #pragma unroll
            for (int i = 0; i < 16; i++) {
                float p = __expf(pv[i] - mn);
                pv[i] = p;
                rs += p;
            }
            rs += __shfl_xor(rs, 16);
            rs += __shfl_xor(rs, 32);
            lrun[s] = lrun[s] * corr + rs;
            acc[s][0] *= corr;
            acc[s][1] *= corr;
            // write P tile to this wave's LDS area (bf16)
            #pragma unroll
            for (int t = 0; t < 4; t++) {
                short4v p4 = { f2bf(pv[t * 4 + 0]), f2bf(pv[t * 4 + 1]),
                               f2bf(pv[t * 4 + 2]), f2bf(pv[t * 4 + 3]) };
                *(short4v*)&Pl[(w * 32 + s * 16 + c) * PSTR + t * 16 + g * 4] = p4;
            }
        }
        // PV: O^T += V^T . P^T  (same-wave LDS RAW; compiler inserts lgkmcnt)
        bf16x8 va[2][2];
        #pragma unroll
        for (int t2 = 0; t2 < 2; t2++)
            #pragma unroll
            for (int kh = 0; kh < 2; kh++)
                va[t2][kh] = *(bf16x8*)&Vt[(t2 * 16 + c) * VSTR + kh * 32 + g * 8];
        #pragma unroll
        for (int s = 0; s < 2; s++)
            #pragma unroll
            for (int kh = 0; kh < 2; kh++) {
                bf16x8 pb = *(bf16x8*)&Pl[(w * 32 + s * 16 + c) * PSTR + kh * 32 + g * 8];
                #pragma unroll
                for (int t2 = 0; t2 < 2; t2++)
                    acc[s][t2] = __builtin_amdgcn_mfma_f32_16x16x32_bf16(va[t2][kh], pb, acc[s][t2], 0, 0, 0);
            }
    }
    // epilogue: O[q][d] = acc^T / l
    #pragma unroll
    for (int s = 0; s < 2; s++) {
        float inv = 1.0f / lrun[s];
        int qrow = qbase + w * 32 + s * 16 + c;
        #pragma unroll
        for (int t2 = 0; t2 < 2; t2++) {
            f32x4 ov = acc[s][t2] * inv;
            *(f32x4*)(Og + bhoff + (size_t)qrow * DM + t2 * 16 + g * 4) = ov;
        }
    }
}

extern "C" void kernel_launch(void* const* d_in, const int* in_sizes, int n_in,
                              void* d_out, int out_size, void* d_ws, size_t ws_size,
                              hipStream_t stream) {
    const int*   logs = (const int*)d_in[0];
    const float* seqs = (const float*)d_in[1];
    const float* Wqkv = (const float*)d_in[2];
    const float* bqkv = (const float*)d_in[3];
    const float* ln1g = (const float*)d_in[4];
    const float* ln1b = (const float*)d_in[5];
    const float* ln2g = (const float*)d_in[6];
    const float* ln2b = (const float*)d_in[7];
    const float* W1   = (const float*)d_in[8];
    const float* b1   = (const float*)d_in[9];
    const float* W2   = (const float*)d_in[10];
    const float* b2   = (const float*)d_in[11];
    const float* lng  = (const float*)d_in[12];
    const float* lnb  = (const float*)d_in[13];
    float* out = (float*)d_out;
    float* ws  = (float*)d_ws;

    size_t ND = (size_t)NROWS * DM;
    float* x    = ws;
    float* qin  = x + ND;
    float* o    = qin + ND;
    float* hbuf = o + ND;
    short* q    = (short*)(hbuf + ND);
    short* k    = q + ND;
    short* v    = k + ND;

    mask_kernel<<<(NROWS * DM) / 4 / 256, 256, 0, stream>>>(seqs, logs, x);

    for (int i = 0; i < NL; i++) {
        const float* Wq = Wqkv + ((size_t)i * 3 + 0) * DM * DM;
        const float* Wk = Wqkv + ((size_t)i * 3 + 1) * DM * DM;
        const float* Wv = Wqkv + ((size_t)i * 3 + 2) * DM * DM;
        const float* bq = bqkv + ((size_t)i * 3 + 0) * DM;
        const float* bk = bqkv + ((size_t)i * 3 + 1) * DM;
        const float* bvp = bqkv + ((size_t)i * 3 + 2) * DM;

        ln_kernel<false, false><<<NROWS / 4, 256, 0, stream>>>(x, nullptr, ln1g + i * DM, ln1b + i * DM, nullptr, qin);

        gemm128_kernel<false, false, false, true><<<NROWS / 64, 256, 0, stream>>>(qin, Wq, bq, nullptr, nullptr, (void*)q);
        gemm128_kernel<false, false, false, true><<<NROWS / 64, 256, 0, stream>>>(x,   Wk, bk, nullptr, nullptr, (void*)k);
        gemm128_kernel<false, false, false, true><<<NROWS / 64, 256, 0, stream>>>(x,   Wv, bvp, nullptr, nullptr, (void*)v);

        attn_mfma_kernel<<<dim3(SS / 128, NH, BB), 256, 0, stream>>>(q, k, v, o);

        // x = LN(qin + attn)
        ln_kernel<true, false><<<NROWS / 4, 256, 0, stream>>>(qin, o, ln2g + i * DM, ln2b + i * DM, nullptr, x);

        // hbuf = relu(x @ W1 + b1)
        gemm128_kernel<true, false, false, false><<<NROWS / 64, 256, 0, stream>>>(x, W1 + (size_t)i * DM * DM, b1 + i * DM, nullptr, nullptr, (void*)hbuf);

        // x = (x + hbuf @ W2 + b2) * keep
        gemm128_kernel<false, true, true, false><<<NROWS / 64, 256, 0, stream>>>(hbuf, W2 + (size_t)i * DM * DM, b2 + i * DM, x, logs, (void*)x);
    }

    // out = LN(x) * keep
    ln_kernel<false, true><<<NROWS / 4, 256, 0, stream>>>(x, nullptr, lng, lnb, logs, out);
}

// Round 9
// 283.781 us; speedup vs baseline: 7.0688x; 1.3387x over previous
//
#include <hip/hip_runtime.h>
#include <hip/hip_bf16.h>
#include <math.h>

#define BB 8
#define SS 2048
#define DM 128
#define NH 4
#define DKH 32
#define NL 2
#define NROWS (BB*SS)   // 16384

typedef __attribute__((ext_vector_type(8))) short bf16x8;
typedef __attribute__((ext_vector_type(4))) short short4v;
typedef __attribute__((ext_vector_type(4))) float f32x4;

#define SCALE 0.17677669529663687f
#define LNEPS 1e-8f

// LDS row strides (shorts)
#define KSTR 40     // K tile rows (32 dk): 5*odd granule -> conflict-free b128
#define VSTR 72     // V^T rows (64 keys): 9*odd granule -> uniform b128
#define PSTR 72     // P rows (64 keys)
#define WTS 136     // W^T rows (128 k): 17*odd granule -> uniform staging+reads

__device__ __forceinline__ short f2bf(float f) {
    union { __hip_bfloat16 h; short s; } u;
    u.h = __float2bfloat16(f);
    return u.s;
}

// ---------------- mask: x = seqs * (log_seqs != 0) ----------------
__global__ __launch_bounds__(256) void mask_kernel(const float* __restrict__ seqs,
                                                   const int* __restrict__ logs,
                                                   float* __restrict__ x) {
    int i4 = blockIdx.x * 256 + threadIdx.x;
    int row = i4 >> 5;
    float4 v = ((const float4*)seqs)[i4];
    float km = (logs[row] != 0) ? 1.0f : 0.0f;
    v.x *= km; v.y *= km; v.z *= km; v.w *= km;
    ((float4*)x)[i4] = v;
}

// ---------------- layernorm over last dim (128); one wave per row ----------------
template<bool HAS_RES, bool HAS_KEEP>
__global__ __launch_bounds__(256) void ln_kernel(const float* __restrict__ X,
                                                 const float* __restrict__ R,
                                                 const float* __restrict__ g,
                                                 const float* __restrict__ bb,
                                                 const int* __restrict__ logs,
                                                 float* __restrict__ Y) {
    int wave = threadIdx.x >> 6, lane = threadIdx.x & 63;
    int row = blockIdx.x * 4 + wave;
    const float2* xp = (const float2*)(X + (size_t)row * DM);
    float2 xv = xp[lane];
    if (HAS_RES) {
        float2 rv = ((const float2*)(R + (size_t)row * DM))[lane];
        xv.x += rv.x; xv.y += rv.y;
    }
    float s = xv.x + xv.y;
    #pragma unroll
    for (int off = 1; off < 64; off <<= 1) s += __shfl_xor(s, off);
    float mean = s * (1.0f / DM);
    float dx = xv.x - mean, dy = xv.y - mean;
    float vs = dx * dx + dy * dy;
    #pragma unroll
    for (int off = 1; off < 64; off <<= 1) vs += __shfl_xor(vs, off);
    float rstd = rsqrtf(vs * (1.0f / DM) + LNEPS);
    float2 gv = ((const float2*)g)[lane];
    float2 bv = ((const float2*)bb)[lane];
    float y0 = dx * rstd * gv.x + bv.x;
    float y1 = dy * rstd * gv.y + bv.y;
    if (HAS_KEEP) {
        float km = (logs[row] != 0) ? 1.0f : 0.0f;
        y0 *= km; y1 *= km;
    }
    float2 o; o.x = y0; o.y = y1;
    ((float2*)(Y + (size_t)row * DM))[lane] = o;
}

// ---------------- MFMA GEMM core: C[N,128] = op(A[N,128] @ W[128,128] + bias) ----
// 256 threads, 64-row tile (wave = 16 rows), W^T staged bf16 in LDS.
// mfma(af,bf,c): D[arow][brow] = sum_k A[arow,k]*B[brow,k]; af=X rows, bf=W cols.
template<bool RELU, bool HAS_RES, bool HAS_KEEP, bool OUT_BF16>
__device__ __forceinline__ void gemm_core(const float* __restrict__ A,
                                          const float* __restrict__ W,
                                          const float* __restrict__ bias,
                                          const float* __restrict__ R,
                                          const int* __restrict__ logs,
                                          void* __restrict__ C) {
    __shared__ short Wt[128 * WTS];   // Wt[j][k] = W[k][j], bf16
    int tid = threadIdx.x;
    int rbase = blockIdx.x * 64;

    {
        int jj = tid & 127;
        int kh = tid >> 7;            // 0 or 1
        #pragma unroll
        for (int i = 0; i < 8; i++) {
            int k8 = kh + i * 2;      // 0..15
            bf16x8 wv;
            #pragma unroll
            for (int kk = 0; kk < 8; kk++)
                wv[kk] = f2bf(W[(k8 * 8 + kk) * DM + jj]);
            *(bf16x8*)&Wt[jj * WTS + k8 * 8] = wv;
        }
    }
    __syncthreads();

    int w = tid >> 6, l = tid & 63;
    int c = l & 15, g = l >> 4;
    int row_a = rbase + w * 16 + c;

    f32x4 acc[8];
    #pragma unroll
    for (int n = 0; n < 8; n++) acc[n] = (f32x4){0.f, 0.f, 0.f, 0.f};

    #pragma unroll
    for (int k0 = 0; k0 < 128; k0 += 32) {
        const float* ap = A + (size_t)row_a * DM + k0 + g * 8;
        float4 a0 = *(const float4*)ap;
        float4 a1 = *(const float4*)(ap + 4);
        bf16x8 af = { f2bf(a0.x), f2bf(a0.y), f2bf(a0.z), f2bf(a0.w),
                      f2bf(a1.x), f2bf(a1.y), f2bf(a1.z), f2bf(a1.w) };
        __builtin_amdgcn_s_setprio(1);
        #pragma unroll
        for (int n = 0; n < 8; n++) {
            bf16x8 bf = *(bf16x8*)&Wt[(n * 16 + c) * WTS + k0 + g * 8];
            acc[n] = __builtin_amdgcn_mfma_f32_16x16x32_bf16(af, bf, acc[n], 0, 0, 0);
        }
        __builtin_amdgcn_s_setprio(0);
    }

    int row0 = rbase + w * 16 + g * 4;
    float km[4];
    if (HAS_KEEP) {
        #pragma unroll
        for (int r = 0; r < 4; r++) km[r] = (logs[row0 + r] != 0) ? 1.0f : 0.0f;
    }
    #pragma unroll
    for (int n = 0; n < 8; n++) {
        float bv = bias[n * 16 + c];
        #pragma unroll
        for (int r = 0; r < 4; r++) {
            float o = acc[n][r] + bv;
            if (RELU) o = fmaxf(o, 0.0f);
            if (HAS_RES) o += R[(size_t)(row0 + r) * DM + n * 16 + c];
            if (HAS_KEEP) o *= km[r];
            size_t idx = (size_t)(row0 + r) * DM + n * 16 + c;
            if (OUT_BF16) ((short*)C)[idx] = f2bf(o);
            else ((float*)C)[idx] = o;
        }
    }
}

template<bool RELU, bool HAS_RES, bool HAS_KEEP, bool OUT_BF16>
__global__ __launch_bounds__(256) void gemm_mfma_kernel(const float* __restrict__ A,
                                                        const float* __restrict__ W,
                                                        const float* __restrict__ bias,
                                                        const float* __restrict__ R,
                                                        const int* __restrict__ logs,
                                                        void* __restrict__ C) {
    gemm_core<RELU, HAS_RES, HAS_KEEP, OUT_BF16>(A, W, bias, R, logs, C);
}

// fused q/k/v: blockIdx.y selects which of the three GEMMs
__global__ __launch_bounds__(256) void gemm_qkv_kernel(const float* __restrict__ qin,
                                                       const float* __restrict__ x,
                                                       const float* __restrict__ Wl,
                                                       const float* __restrict__ bl,
                                                       short* __restrict__ qkv) {
    int y = blockIdx.y;
    const float* A = (y == 0) ? qin : x;
    gemm_core<false, false, false, true>(A, Wl + (size_t)y * DM * DM, bl + y * DM,
                                         nullptr, nullptr,
                                         (void*)(qkv + (size_t)y * NROWS * DM));
}

// ---------------- MFMA flash attention (bf16 in, f32 out) ----------------
// grid: (S/64, H, B); block 256 = 4 waves, each wave owns 16 q-rows.
// S^T = K.Q^T so all lane values share one q-row; O^T = V^T.P^T.
__global__ __launch_bounds__(256) void attn_mfma_kernel(const short* __restrict__ Qg,
                                                        const short* __restrict__ Kg,
                                                        const short* __restrict__ Vg,
                                                        float* __restrict__ Og) {
    __shared__ short Ks[64 * KSTR];     // K tile [key][dk]
    __shared__ short Vt[32 * VSTR];     // V^T tile [dk][key]
    __shared__ short Pl[64 * PSTR];     // P [q][key], 4 waves x 16 rows

    int tid = threadIdx.x;
    int qt = (gridDim.x - 1) - blockIdx.x;    // heavy (high-q) blocks first
    int h = blockIdx.y, b = blockIdx.z;
    int w = tid >> 6, l = tid & 63;
    int c = l & 15, g = l >> 4;

    int qbase = qt * 64;
    int qrow = qbase + w * 16 + c;
    int wqmin = qbase + w * 16;
    size_t bhoff = (size_t)b * SS * DM + (size_t)h * DKH;

    bf16x8 qf = *(const bf16x8*)(Qg + bhoff + (size_t)qrow * DM + g * 8);
    f32x4 acc[2] = { (f32x4){0,0,0,0}, (f32x4){0,0,0,0} };
    float mrun = -1e30f, lrun = 0.f;
    int ntiles = qt + 1;

    int kkey = tid >> 2, kpart = tid & 3;
    int vkey = tid & 63, vpart = tid >> 6;

    for (int kt = 0; kt < ntiles; kt++) {
        int kb = kt * 64;
        __syncthreads();
        bf16x8 kv8 = *(const bf16x8*)(Kg + bhoff + (size_t)(kb + kkey) * DM + kpart * 8);
        *(bf16x8*)&Ks[kkey * KSTR + kpart * 8] = kv8;
        bf16x8 vv8 = *(const bf16x8*)(Vg + bhoff + (size_t)(kb + vkey) * DM + vpart * 8);
        #pragma unroll
        for (int j = 0; j < 8; j++) Vt[(vpart * 8 + j) * VSTR + vkey] = vv8[j];
        __syncthreads();

        bf16x8 kf[4];
        #pragma unroll
        for (int t = 0; t < 4; t++)
            kf[t] = *(bf16x8*)&Ks[(t * 16 + c) * KSTR + g * 8];

        f32x4 z = {0.f, 0.f, 0.f, 0.f};
        f32x4 sc[4];
        __builtin_amdgcn_s_setprio(1);
        #pragma unroll
        for (int t = 0; t < 4; t++)
            sc[t] = __builtin_amdgcn_mfma_f32_16x16x32_bf16(kf[t], qf, z, 0, 0, 0);
        __builtin_amdgcn_s_setprio(0);

        float pv[16];
        float mx = -1e30f;
        if ((kb + 63) > wqmin) {           // diagonal tile only (wave-uniform)
            #pragma unroll
            for (int t = 0; t < 4; t++)
                #pragma unroll
                for (int r = 0; r < 4; r++) {
                    int kg = kb + t * 16 + g * 4 + r;
                    float v2 = (kg <= qrow) ? sc[t][r] * SCALE : -1e30f;
                    pv[t * 4 + r] = v2;
                    mx = fmaxf(mx, v2);
                }
        } else {
            #pragma unroll
            for (int t = 0; t < 4; t++)
                #pragma unroll
                for (int r = 0; r < 4; r++) {
                    float v2 = sc[t][r] * SCALE;
                    pv[t * 4 + r] = v2;
                    mx = fmaxf(mx, v2);
                }
        }
        mx = fmaxf(mx, __shfl_xor(mx, 16));
        mx = fmaxf(mx, __shfl_xor(mx, 32));
        float mn = fmaxf(mrun, mx);
        float corr = __expf(mrun - mn);
        mrun = mn;
        float rs = 0.f;
        #pragma unroll
        for (int i = 0; i < 16; i++) {
            float p = __expf(pv[i] - mn);
            pv[i] = p;
            rs += p;
        }
        rs += __shfl_xor(rs, 16);
        rs += __shfl_xor(rs, 32);
        lrun = lrun * corr + rs;
        acc[0] *= corr;
        acc[1] *= corr;

        #pragma unroll
        for (int t = 0; t < 4; t++) {
            short4v p4 = { f2bf(pv[t * 4 + 0]), f2bf(pv[t * 4 + 1]),
                           f2bf(pv[t * 4 + 2]), f2bf(pv[t * 4 + 3]) };
            *(short4v*)&Pl[(w * 16 + c) * PSTR + t * 16 + g * 4] = p4;
        }
        bf16x8 va[2][2];
        #pragma unroll
        for (int t2 = 0; t2 < 2; t2++)
            #pragma unroll
            for (int kh = 0; kh < 2; kh++)
                va[t2][kh] = *(bf16x8*)&Vt[(t2 * 16 + c) * VSTR + kh * 32 + g * 8];
        bf16x8 pb[2];
        #pragma unroll
        for (int kh = 0; kh < 2; kh++)
            pb[kh] = *(bf16x8*)&Pl[(w * 16 + c) * PSTR + kh * 32 + g * 8];
        __builtin_amdgcn_s_setprio(1);
        #pragma unroll
        for (int kh = 0; kh < 2; kh++)
            #pragma unroll
            for (int t2 = 0; t2 < 2; t2++)
                acc[t2] = __builtin_amdgcn_mfma_f32_16x16x32_bf16(va[t2][kh], pb[kh], acc[t2], 0, 0, 0);
        __builtin_amdgcn_s_setprio(0);
    }
    float inv = 1.0f / lrun;
    #pragma unroll
    for (int t2 = 0; t2 < 2; t2++) {
        f32x4 ov = acc[t2] * inv;
        *(f32x4*)(Og + bhoff + (size_t)qrow * DM + t2 * 16 + g * 4) = ov;
    }
}

extern "C" void kernel_launch(void* const* d_in, const int* in_sizes, int n_in,
                              void* d_out, int out_size, void* d_ws, size_t ws_size,
                              hipStream_t stream) {
    const int*   logs = (const int*)d_in[0];
    const float* seqs = (const float*)d_in[1];
    const float* Wqkv = (const float*)d_in[2];
    const float* bqkv = (const float*)d_in[3];
    const float* ln1g = (const float*)d_in[4];
    const float* ln1b = (const float*)d_in[5];
    const float* ln2g = (const float*)d_in[6];
    const float* ln2b = (const float*)d_in[7];
    const float* W1   = (const float*)d_in[8];
    const float* b1   = (const float*)d_in[9];
    const float* W2   = (const float*)d_in[10];
    const float* b2   = (const float*)d_in[11];
    const float* lng  = (const float*)d_in[12];
    const float* lnb  = (const float*)d_in[13];
    float* out = (float*)d_out;
    float* ws  = (float*)d_ws;

    size_t ND = (size_t)NROWS * DM;
    float* x    = ws;
    float* qin  = x + ND;
    float* o    = qin + ND;
    float* hbuf = o + ND;
    short* qkv  = (short*)(hbuf + ND);
    short* q    = qkv;
    short* k    = qkv + ND;
    short* v    = qkv + 2 * ND;

    mask_kernel<<<(NROWS * DM) / 4 / 256, 256, 0, stream>>>(seqs, logs, x);

    for (int i = 0; i < NL; i++) {
        ln_kernel<false, false><<<NROWS / 4, 256, 0, stream>>>(x, nullptr, ln1g + i * DM, ln1b + i * DM, nullptr, qin);

        gemm_qkv_kernel<<<dim3(NROWS / 64, 3), 256, 0, stream>>>(qin, x,
            Wqkv + (size_t)i * 3 * DM * DM, bqkv + (size_t)i * 3 * DM, qkv);

        attn_mfma_kernel<<<dim3(SS / 64, NH, BB), 256, 0, stream>>>(q, k, v, o);

        // x = LN(qin + attn)
        ln_kernel<true, false><<<NROWS / 4, 256, 0, stream>>>(qin, o, ln2g + i * DM, ln2b + i * DM, nullptr, x);

        // hbuf = relu(x @ W1 + b1)
        gemm_mfma_kernel<true, false, false, false><<<NROWS / 64, 256, 0, stream>>>(x, W1 + (size_t)i * DM * DM, b1 + i * DM, nullptr, nullptr, (void*)hbuf);

        // x = (x + hbuf @ W2 + b2) * keep
        gemm_mfma_kernel<false, true, true, false><<<NROWS / 64, 256, 0, stream>>>(hbuf, W2 + (size_t)i * DM * DM, b2 + i * DM, x, logs, (void*)x);
    }

    // out = LN(x) * keep
    ln_kernel<false, true><<<NROWS / 4, 256, 0, stream>>>(x, nullptr, lng, lnb, logs, out);
}

// Round 15
// 275.861 us; speedup vs baseline: 7.2717x; 1.0287x over previous
//
#include <hip/hip_runtime.h>
#include <hip/hip_bf16.h>
#include <math.h>

#define BB 8
#define SS 2048
#define DM 128
#define NH 4
#define DKH 32
#define NL 2
#define NROWS (BB*SS)   // 16384

typedef __attribute__((ext_vector_type(8))) short bf16x8;
typedef __attribute__((ext_vector_type(4))) short short4v;
typedef __attribute__((ext_vector_type(4))) float f32x4;

#define SCALE 0.17677669529663687f
#define LNEPS 1e-8f

// LDS row strides (shorts) for attention tiles
#define KSTR 40     // K tile rows (32 dk)
#define VSTR 72     // V^T rows (64 keys)
#define PSTR 72     // P rows (64 keys)

__device__ __forceinline__ short f2bf(float f) {
    union { __hip_bfloat16 h; short s; } u;
    u.h = __float2bfloat16(f);
    return u.s;
}

// ---------------- mask: x = seqs * (log_seqs != 0) ----------------
__global__ __launch_bounds__(256) void mask_kernel(const float* __restrict__ seqs,
                                                   const int* __restrict__ logs,
                                                   float* __restrict__ x) {
    int i4 = blockIdx.x * 256 + threadIdx.x;
    int row = i4 >> 5;
    float4 v = ((const float4*)seqs)[i4];
    float km = (logs[row] != 0) ? 1.0f : 0.0f;
    v.x *= km; v.y *= km; v.z *= km; v.w *= km;
    ((float4*)x)[i4] = v;
}

// ---------------- layernorm over last dim (128); one wave per row ----------------
template<bool HAS_RES, bool HAS_KEEP>
__global__ __launch_bounds__(256) void ln_kernel(const float* __restrict__ X,
                                                 const float* __restrict__ R,
                                                 const float* __restrict__ g,
                                                 const float* __restrict__ bb,
                                                 const int* __restrict__ logs,
                                                 float* __restrict__ Y) {
    int wave = threadIdx.x >> 6, lane = threadIdx.x & 63;
    int row = blockIdx.x * 4 + wave;
    const float2* xp = (const float2*)(X + (size_t)row * DM);
    float2 xv = xp[lane];
    if (HAS_RES) {
        float2 rv = ((const float2*)(R + (size_t)row * DM))[lane];
        xv.x += rv.x; xv.y += rv.y;
    }
    float s = xv.x + xv.y;
    #pragma unroll
    for (int off = 1; off < 64; off <<= 1) s += __shfl_xor(s, off);
    float mean = s * (1.0f / DM);
    float dx = xv.x - mean, dy = xv.y - mean;
    float vs = dx * dx + dy * dy;
    #pragma unroll
    for (int off = 1; off < 64; off <<= 1) vs += __shfl_xor(vs, off);
    float rstd = rsqrtf(vs * (1.0f / DM) + LNEPS);
    float2 gv = ((const float2*)g)[lane];
    float2 bv = ((const float2*)bb)[lane];
    float y0 = dx * rstd * gv.x + bv.x;
    float y1 = dy * rstd * gv.y + bv.y;
    if (HAS_KEEP) {
        float km = (logs[row] != 0) ? 1.0f : 0.0f;
        y0 *= km; y1 *= km;
    }
    float2 o; o.x = y0; o.y = y1;
    ((float2*)(Y + (size_t)row * DM))[lane] = o;
}

// ---------------- weight prep: f32 W[k][j] -> bf16 image[j][k ^ ((j&7)<<3)] ------
// One-time per launch. 80 blocks: (matrix m 0..9) x (16-row j-band jg 0..7).
// Image is the exact per-block LDS layout the GEMM stages linearly, with the
// b128 read swizzle baked into the source (pre-swizzled-global pattern).
__global__ __launch_bounds__(256) void prep_w_kernel(const float* __restrict__ Wqkv,
                                                     const float* __restrict__ W1,
                                                     const float* __restrict__ W2,
                                                     short* __restrict__ wimg) {
    __shared__ short tile[16 * 128];   // 4 KB
    int bid = blockIdx.x;
    int m = bid >> 3, jg = bid & 7;
    const float* src = (m < 6) ? (Wqkv + (size_t)m * 16384)
                     : (m < 8) ? (W1 + (size_t)(m - 6) * 16384)
                               : (W2 + (size_t)(m - 8) * 16384);
    int tid = threadIdx.x;
    #pragma unroll
    for (int it = 0; it < 8; it++) {
        int e = it * 256 + tid;        // 0..2047
        int jj = e & 15;               // col within 16-wide band
        int k  = e >> 4;               // source row 0..127
        float v = src[(size_t)k * DM + jg * 16 + jj];
        tile[jj * 128 + (k ^ ((jj & 7) << 3))] = f2bf(v);
    }
    __syncthreads();
    short* dst = wimg + (size_t)m * 16384 + jg * 2048;
    *(bf16x8*)&dst[tid * 8] = *(bf16x8*)&tile[tid * 8];
}

// ---------------- MFMA GEMM core: C[N,128] = op(A[N,128] @ W[128,128] + bias) ----
// 256 threads, 64-row tile. W comes pre-converted/pre-swizzled bf16 (wimg):
// staging = 8x16B vector load + 8 linear b128 LDS writes per thread (no cvt).
// Reads: Wt[row*128 + ((k0+g*8) ^ ((row&7)<<3))] -> conflict-free b128.
template<bool RELU, bool HAS_RES, bool HAS_KEEP, bool OUT_BF16>
__device__ __forceinline__ void gemm_core(const float* __restrict__ A,
                                          const short* __restrict__ Wimg,
                                          const float* __restrict__ bias,
                                          const float* __restrict__ R,
                                          const int* __restrict__ logs,
                                          void* __restrict__ C) {
    __shared__ short Wt[128 * 128];   // 32 KB, linear copy of the swizzled image
    int tid = threadIdx.x;
    int rbase = blockIdx.x * 64;

    #pragma unroll
    for (int it = 0; it < 8; it++) {
        int e = it * 256 + tid;        // 16B-unit index 0..2047
        bf16x8 wv = *(const bf16x8*)(Wimg + (size_t)e * 8);
        *(bf16x8*)&Wt[e * 8] = wv;
    }
    __syncthreads();

    int w = tid >> 6, l = tid & 63;
    int c = l & 15, g = l >> 4;
    int row_a = rbase + w * 16 + c;
    int c7s = (c & 7) << 3;

    f32x4 acc[8];
    #pragma unroll
    for (int n = 0; n < 8; n++) acc[n] = (f32x4){0.f, 0.f, 0.f, 0.f};

    #pragma unroll
    for (int k0 = 0; k0 < 128; k0 += 32) {
        const float* ap = A + (size_t)row_a * DM + k0 + g * 8;
        float4 a0 = *(const float4*)ap;
        float4 a1 = *(const float4*)(ap + 4);
        bf16x8 af = { f2bf(a0.x), f2bf(a0.y), f2bf(a0.z), f2bf(a0.w),
                      f2bf(a1.x), f2bf(a1.y), f2bf(a1.z), f2bf(a1.w) };
        __builtin_amdgcn_s_setprio(1);
        #pragma unroll
        for (int n = 0; n < 8; n++) {
            int row = n * 16 + c;
            bf16x8 bf = *(bf16x8*)&Wt[row * 128 + ((k0 + g * 8) ^ c7s)];
            acc[n] = __builtin_amdgcn_mfma_f32_16x16x32_bf16(af, bf, acc[n], 0, 0, 0);
        }
        __builtin_amdgcn_s_setprio(0);
    }

    int row0 = rbase + w * 16 + g * 4;
    float km[4];
    if (HAS_KEEP) {
        #pragma unroll
        for (int r = 0; r < 4; r++) km[r] = (logs[row0 + r] != 0) ? 1.0f : 0.0f;
    }
    #pragma unroll
    for (int n = 0; n < 8; n++) {
        float bv = bias[n * 16 + c];
        #pragma unroll
        for (int r = 0; r < 4; r++) {
            float o = acc[n][r] + bv;
            if (RELU) o = fmaxf(o, 0.0f);
            if (HAS_RES) o += R[(size_t)(row0 + r) * DM + n * 16 + c];
            if (HAS_KEEP) o *= km[r];
            size_t idx = (size_t)(row0 + r) * DM + n * 16 + c;
            if (OUT_BF16) ((short*)C)[idx] = f2bf(o);
            else ((float*)C)[idx] = o;
        }
    }
}

template<bool RELU, bool HAS_RES, bool HAS_KEEP, bool OUT_BF16>
__global__ __launch_bounds__(256) void gemm_mfma_kernel(const float* __restrict__ A,
                                                        const short* __restrict__ Wimg,
                                                        const float* __restrict__ bias,
                                                        const float* __restrict__ R,
                                                        const int* __restrict__ logs,
                                                        void* __restrict__ C) {
    gemm_core<RELU, HAS_RES, HAS_KEEP, OUT_BF16>(A, Wimg, bias, R, logs, C);
}

// fused q/k/v: blockIdx.y selects which of the three GEMMs
__global__ __launch_bounds__(256) void gemm_qkv_kernel(const float* __restrict__ qin,
                                                       const float* __restrict__ x,
                                                       const short* __restrict__ Wimgl,
                                                       const float* __restrict__ bl,
                                                       short* __restrict__ qkv) {
    int y = blockIdx.y;
    const float* A = (y == 0) ? qin : x;
    gemm_core<false, false, false, true>(A, Wimgl + (size_t)y * 16384, bl + y * DM,
                                         nullptr, nullptr,
                                         (void*)(qkv + (size_t)y * NROWS * DM));
}

// ---------------- MFMA flash attention (bf16 in, f32 out) ----------------
// grid: (S/64, H, B); block 256 = 4 waves, each wave owns 16 q-rows.
// S^T = K.Q^T so all lane values share one q-row; O^T = V^T.P^T.
// T14: next-tile K/V loads issued before compute (latency hidden under softmax).
// T13: defer-max rescale with THR=8.
__global__ __launch_bounds__(256) void attn_mfma_kernel(const short* __restrict__ Qg,
                                                        const short* __restrict__ Kg,
                                                        const short* __restrict__ Vg,
                                                        float* __restrict__ Og) {
    __shared__ short Ks[64 * KSTR];     // K tile [key][dk]
    __shared__ short Vt[32 * VSTR];     // V^T tile [dk][key]
    __shared__ short Pl[64 * PSTR];     // P [q][key], 4 waves x 16 rows

    int tid = threadIdx.x;
    int qt = (gridDim.x - 1) - blockIdx.x;    // heavy (high-q) blocks first
    int h = blockIdx.y, b = blockIdx.z;
    int w = tid >> 6, l = tid & 63;
    int c = l & 15, g = l >> 4;

    int qbase = qt * 64;
    int qrow = qbase + w * 16 + c;
    int wqmin = qbase + w * 16;
    size_t bhoff = (size_t)b * SS * DM + (size_t)h * DKH;

    bf16x8 qf = *(const bf16x8*)(Qg + bhoff + (size_t)qrow * DM + g * 8);
    f32x4 acc[2] = { (f32x4){0,0,0,0}, (f32x4){0,0,0,0} };
    float mrun = -1e30f, lrun = 0.f;
    int ntiles = qt + 1;

    int kkey = tid >> 2, kpart = tid & 3;
    int vkey = tid & 63, vpart = tid >> 6;

    // prologue: tile-0 loads in flight
    bf16x8 kv8 = *(const bf16x8*)(Kg + bhoff + (size_t)kkey * DM + kpart * 8);
    bf16x8 vv8 = *(const bf16x8*)(Vg + bhoff + (size_t)vkey * DM + vpart * 8);

    for (int kt = 0; kt < ntiles; kt++) {
        int kb = kt * 64;
        __syncthreads();                 // prev compute done reading LDS
        *(bf16x8*)&Ks[kkey * KSTR + kpart * 8] = kv8;
        #pragma unroll
        for (int j = 0; j < 8; j++) Vt[(vpart * 8 + j) * VSTR + vkey] = vv8[j];
        if (kt + 1 < ntiles) {           // issue next-tile loads; consumed next iter
            int kb2 = kb + 64;
            kv8 = *(const bf16x8*)(Kg + bhoff + (size_t)(kb2 + kkey) * DM + kpart * 8);
            vv8 = *(const bf16x8*)(Vg + bhoff + (size_t)(kb2 + vkey) * DM + vpart * 8);
        }
        __syncthreads();                 // LDS tile ready

        bf16x8 kf[4];
        #pragma unroll
        for (int t = 0; t < 4; t++)
            kf[t] = *(bf16x8*)&Ks[(t * 16 + c) * KSTR + g * 8];

        f32x4 z = {0.f, 0.f, 0.f, 0.f};
        f32x4 sc[4];
        __builtin_amdgcn_s_setprio(1);
        #pragma unroll
        for (int t = 0; t < 4; t++)
            sc[t] = __builtin_amdgcn_mfma_f32_16x16x32_bf16(kf[t], qf, z, 0, 0, 0);
        __builtin_amdgcn_s_setprio(0);

        float pv[16];
        float mx = -1e30f;
        if ((kb + 63) > wqmin) {           // diagonal tile only (wave-uniform)
            #pragma unroll
            for (int t = 0; t < 4; t++)
                #pragma unroll
                for (int r = 0; r < 4; r++) {
                    int kg = kb + t * 16 + g * 4 + r;
                    float v2 = (kg <= qrow) ? sc[t][r] * SCALE : -1e30f;
                    pv[t * 4 + r] = v2;
                    mx = fmaxf(mx, v2);
                }
        } else {
            #pragma unroll
            for (int t = 0; t < 4; t++)
                #pragma unroll
                for (int r = 0; r < 4; r++) {
                    float v2 = sc[t][r] * SCALE;
                    pv[t * 4 + r] = v2;
                    mx = fmaxf(mx, v2);
                }
        }
        mx = fmaxf(mx, __shfl_xor(mx, 16));
        mx = fmaxf(mx, __shfl_xor(mx, 32));
        // T13 defer-max: skip rescale while tile max stays within THR of running max
        if (!__all(mx - mrun <= 8.0f)) {
            float mn = fmaxf(mrun, mx);
            float corr = __expf(mrun - mn);
            lrun *= corr;
            acc[0] *= corr;
            acc[1] *= corr;
            mrun = mn;
        }
        float rs = 0.f;
        #pragma unroll
        for (int i = 0; i < 16; i++) {
            float p = __expf(pv[i] - mrun);
            pv[i] = p;
            rs += p;
        }
        rs += __shfl_xor(rs, 16);
        rs += __shfl_xor(rs, 32);
        lrun += rs;

        #pragma unroll
        for (int t = 0; t < 4; t++) {
            short4v p4 = { f2bf(pv[t * 4 + 0]), f2bf(pv[t * 4 + 1]),
                           f2bf(pv[t * 4 + 2]), f2bf(pv[t * 4 + 3]) };
            *(short4v*)&Pl[(w * 16 + c) * PSTR + t * 16 + g * 4] = p4;
        }
        bf16x8 va[2][2];
        #pragma unroll
        for (int t2 = 0; t2 < 2; t2++)
            #pragma unroll
            for (int kh = 0; kh < 2; kh++)
                va[t2][kh] = *(bf16x8*)&Vt[(t2 * 16 + c) * VSTR + kh * 32 + g * 8];
        bf16x8 pb[2];
        #pragma unroll
        for (int kh = 0; kh < 2; kh++)
            pb[kh] = *(bf16x8*)&Pl[(w * 16 + c) * PSTR + kh * 32 + g * 8];
        __builtin_amdgcn_s_setprio(1);
        #pragma unroll
        for (int kh = 0; kh < 2; kh++)
            #pragma unroll
            for (int t2 = 0; t2 < 2; t2++)
                acc[t2] = __builtin_amdgcn_mfma_f32_16x16x32_bf16(va[t2][kh], pb[kh], acc[t2], 0, 0, 0);
        __builtin_amdgcn_s_setprio(0);
    }
    float inv = 1.0f / lrun;
    #pragma unroll
    for (int t2 = 0; t2 < 2; t2++) {
        f32x4 ov = acc[t2] * inv;
        *(f32x4*)(Og + bhoff + (size_t)qrow * DM + t2 * 16 + g * 4) = ov;
    }
}

extern "C" void kernel_launch(void* const* d_in, const int* in_sizes, int n_in,
                              void* d_out, int out_size, void* d_ws, size_t ws_size,
                              hipStream_t stream) {
    const int*   logs = (const int*)d_in[0];
    const float* seqs = (const float*)d_in[1];
    const float* Wqkv = (const float*)d_in[2];
    const float* bqkv = (const float*)d_in[3];
    const float* ln1g = (const float*)d_in[4];
    const float* ln1b = (const float*)d_in[5];
    const float* ln2g = (const float*)d_in[6];
    const float* ln2b = (const float*)d_in[7];
    const float* W1   = (const float*)d_in[8];
    const float* b1   = (const float*)d_in[9];
    const float* W2   = (const float*)d_in[10];
    const float* b2   = (const float*)d_in[11];
    const float* lng  = (const float*)d_in[12];
    const float* lnb  = (const float*)d_in[13];
    float* out = (float*)d_out;
    float* ws  = (float*)d_ws;

    size_t ND = (size_t)NROWS * DM;
    float* x    = ws;
    float* qin  = x + ND;
    float* o    = qin + ND;
    float* hbuf = o + ND;
    short* qkv  = (short*)(hbuf + ND);
    short* q    = qkv;
    short* k    = qkv + ND;
    short* v    = qkv + 2 * ND;
    short* wimg = qkv + 3 * ND;          // 10 x 16384 bf16 weight images

    prep_w_kernel<<<80, 256, 0, stream>>>(Wqkv, W1, W2, wimg);
    mask_kernel<<<(NROWS * DM) / 4 / 256, 256, 0, stream>>>(seqs, logs, x);

    for (int i = 0; i < NL; i++) {
        ln_kernel<false, false><<<NROWS / 4, 256, 0, stream>>>(x, nullptr, ln1g + i * DM, ln1b + i * DM, nullptr, qin);

        gemm_qkv_kernel<<<dim3(NROWS / 64, 3), 256, 0, stream>>>(qin, x,
            wimg + (size_t)(i * 3) * 16384, bqkv + (size_t)i * 3 * DM, qkv);

        attn_mfma_kernel<<<dim3(SS / 64, NH, BB), 256, 0, stream>>>(q, k, v, o);

        // x = LN(qin + attn)
        ln_kernel<true, false><<<NROWS / 4, 256, 0, stream>>>(qin, o, ln2g + i * DM, ln2b + i * DM, nullptr, x);

        // hbuf = relu(x @ W1 + b1)
        gemm_mfma_kernel<true, false, false, false><<<NROWS / 64, 256, 0, stream>>>(x, wimg + (size_t)(6 + i) * 16384, b1 + i * DM, nullptr, nullptr, (void*)hbuf);

        // x = (x + hbuf @ W2 + b2) * keep
        gemm_mfma_kernel<false, true, true, false><<<NROWS / 64, 256, 0, stream>>>(hbuf, wimg + (size_t)(8 + i) * 16384, b2 + i * DM, x, logs, (void*)x);
    }

    // out = LN(x) * keep
    ln_kernel<false, true><<<NROWS / 4, 256, 0, stream>>>(x, nullptr, lng, lnb, logs, out);
}